// Round 1
// baseline (470.482 us; speedup 1.0000x reference)
//
#include <hip/hip_runtime.h>
#include <math.h>

#define NSEG 8192
#define D 32
#define EPSF 1e-10f
#define BLK 256
#define WPB 4   // waves per block (one wave per segment)

// ---------------------------------------------------------------------------
// seg_start[s] = first row index i with batch[i] >= s  (batch is sorted).
// seg_start has NSEG+1 entries; seg_start[NSEG] = N. Lives in d_ws.
// ---------------------------------------------------------------------------
__global__ void init_starts_kernel(int* __restrict__ seg_start, int N) {
    int s = blockIdx.x * blockDim.x + threadIdx.x;
    if (s <= NSEG) seg_start[s] = N;   // default: empty tail segments
}

__global__ void find_starts_kernel(const int* __restrict__ batch,
                                   int* __restrict__ seg_start, int N) {
    int i = blockIdx.x * blockDim.x + threadIdx.x;
    if (i >= N) return;
    int b = batch[i];
    int prev = (i == 0) ? -1 : batch[i - 1];
    // almost always 0 or 1 iterations (segments are dense)
    for (int s = prev + 1; s <= b; ++s) seg_start[s] = i;
}

// ---------------------------------------------------------------------------
// One WAVE per segment. Lane l: col-group cg = l&7 (4 floats), row-group
// rg = l>>3 handles rows rg, rg+8, ... Each iteration the wave touches
// 8 consecutive rows = 1 KB contiguous (perfectly coalesced float4).
//
// No LDS at all: per-segment data (~31 KB) is L1/L2/L3 resident between the
// two passes, and all reductions are intra-wave shfl_xor (masks 8/16/32
// collapse the rg dimension). Pass 1 keeps an online (max, sum) pair per
// component so x is read exactly twice. Output is stored nontemporally so
// the out-stream doesn't evict x from L2/L3.
// ---------------------------------------------------------------------------
typedef float v4f __attribute__((ext_vector_type(4)));

__device__ __forceinline__ v4f shfl_xor_v4(v4f v, int mask) {
    v4f r;
    r.x = __shfl_xor(v.x, mask, 64);
    r.y = __shfl_xor(v.y, mask, 64);
    r.z = __shfl_xor(v.z, mask, 64);
    r.w = __shfl_xor(v.w, mask, 64);
    return r;
}

// online-softmax accumulate: (m,l) += value v
#define ONLINE_ACC(c)                                          \
    {                                                          \
        float mn = fmaxf(m.c, v.c);                            \
        l.c = l.c * __expf(m.c - mn) + __expf(v.c - mn);       \
        m.c = mn;                                              \
    }

// online-softmax merge: (m,l) += (m2,l2)
#define ONLINE_MERGE(c)                                        \
    {                                                          \
        float mn = fmaxf(m.c, m2.c);                           \
        l.c = l.c * __expf(m.c - mn) + l2.c * __expf(m2.c - mn); \
        m.c = mn;                                              \
    }

__global__ __launch_bounds__(BLK, 8) void seg_softmax_wave(
    const float* __restrict__ x, const int* __restrict__ seg_start,
    float* __restrict__ out)
{
    const int tid  = (int)threadIdx.x;
    const int lane = tid & 63;
    const int s    = blockIdx.x * WPB + (tid >> 6);   // grid = NSEG/WPB exactly

    const int start = seg_start[s];
    const int len   = seg_start[s + 1] - start;
    if (len <= 0) return;   // empty segment: nothing to write

    const int cg = lane & 7;    // col group (4 floats)
    const int rg = lane >> 3;   // row group 0..7

    const v4f* __restrict__ xin = (const v4f*)(x + (size_t)start * D);
    v4f* __restrict__       outv = (v4f*)(out + (size_t)start * D);

    // Finite sentinel (NOT -inf): merging two empty lanes must not produce
    // exp(-inf - -inf) = NaN. exp(-1e30 - finite) underflows cleanly to 0.
    const float LOW = -1e30f;
    v4f m = {LOW, LOW, LOW, LOW};
    v4f l = {0.f, 0.f, 0.f, 0.f};

    // ---- pass 1: online column (max, sum) over this lane's rows ----
    for (int r = rg; r < len; r += 8) {
        v4f v = xin[r * 8 + cg];
        ONLINE_ACC(x) ONLINE_ACC(y) ONLINE_ACC(z) ONLINE_ACC(w)
    }

    // ---- reduce (m,l) across row-groups: lane bits 3..5 ----
    #pragma unroll
    for (int mask = 8; mask <= 32; mask <<= 1) {
        v4f m2 = shfl_xor_v4(m, mask);
        v4f l2 = shfl_xor_v4(l, mask);
        ONLINE_MERGE(x) ONLINE_MERGE(y) ONLINE_MERGE(z) ONLINE_MERGE(w)
    }

    v4f rn;
    rn.x = 1.f / (l.x + EPSF);
    rn.y = 1.f / (l.y + EPSF);
    rn.z = 1.f / (l.z + EPSF);
    rn.w = 1.f / (l.w + EPSF);

    // ---- pass 2: recompute exp (x re-read is cache-warm), scale, store ----
    for (int r = rg; r < len; r += 8) {
        v4f v = xin[r * 8 + cg];
        v4f e;
        e.x = __expf(v.x - m.x) * rn.x;
        e.y = __expf(v.y - m.y) * rn.y;
        e.z = __expf(v.z - m.z) * rn.z;
        e.w = __expf(v.w - m.w) * rn.w;
        __builtin_nontemporal_store(e, &outv[r * 8 + cg]);
    }
}

// ---------------------------------------------------------------------------
extern "C" void kernel_launch(void* const* d_in, const int* in_sizes, int n_in,
                              void* d_out, int out_size, void* d_ws, size_t ws_size,
                              hipStream_t stream) {
    const int*   batch = (const int*)d_in[0];
    const float* x     = (const float*)d_in[1];
    float*       out   = (float*)d_out;
    const int    N     = in_sizes[0];

    int* seg_start = (int*)d_ws;   // (NSEG+1) ints; re-initialized every call

    init_starts_kernel<<<(NSEG + 1 + 255) / 256, 256, 0, stream>>>(seg_start, N);
    find_starts_kernel<<<(N + 255) / 256, 256, 0, stream>>>(batch, seg_start, N);
    seg_softmax_wave<<<NSEG / WPB, BLK, 0, stream>>>(x, seg_start, out);
}

// Round 2
// 440.922 us; speedup vs baseline: 1.0670x; 1.0670x over previous
//
#include <hip/hip_runtime.h>
#include <math.h>

#define NSEG 8192
#define D 32
#define EPSF 1e-10f
#define BLK 256
#define K_CAP 10   // staged 32-row tiles per block: covers segments up to 320 rows

// ---------------------------------------------------------------------------
// seg_start[s] = first row index i with batch[i] >= s  (batch is sorted).
// seg_start has NSEG+1 entries; seg_start[NSEG] = N. Lives in d_ws.
// ---------------------------------------------------------------------------
__global__ void init_starts_kernel(int* __restrict__ seg_start, int N) {
    int s = blockIdx.x * blockDim.x + threadIdx.x;
    if (s <= NSEG) seg_start[s] = N;   // default: empty tail segments
}

__global__ void find_starts_kernel(const int* __restrict__ batch,
                                   int* __restrict__ seg_start, int N) {
    int i = blockIdx.x * blockDim.x + threadIdx.x;
    if (i >= N) return;
    int b = batch[i];
    int prev = (i == 0) ? -1 : batch[i - 1];
    // almost always 0 or 1 iterations (segments are dense)
    for (int s = prev + 1; s <= b; ++s) seg_start[s] = i;
}

// ---------------------------------------------------------------------------
typedef float v4f __attribute__((ext_vector_type(4)));

__device__ __forceinline__ v4f v4max(v4f a, v4f b) {
    v4f r;
    r.x = fmaxf(a.x, b.x); r.y = fmaxf(a.y, b.y);
    r.z = fmaxf(a.z, b.z); r.w = fmaxf(a.w, b.w);
    return r;
}
__device__ __forceinline__ v4f shfl_xor_v4(v4f v, int mask) {
    v4f r;
    r.x = __shfl_xor(v.x, mask, 64);
    r.y = __shfl_xor(v.y, mask, 64);
    r.z = __shfl_xor(v.z, mask, 64);
    r.w = __shfl_xor(v.w, mask, 64);
    return r;
}

// ---------------------------------------------------------------------------
// One block (4 waves) per segment. Thread t: col-group cg = t&7 (4 floats),
// row rg = t>>3 within each 32-row tile; tile k holds rows rg + 32k.
// The whole segment (<=320 rows) is staged in REGISTERS (K_CAP v4f = 40 VGPR
// per lane), with all loads issued as one independent batch so ~10 KB/wave is
// in flight (the round-1 kernel kept ~1 load in flight -> latency-bound at
// 2.8 TB/s). Read-once, one exp/element, 512 B LDS for cross-wave reduction.
// ---------------------------------------------------------------------------
__global__ __launch_bounds__(BLK, 5) void seg_softmax_reg(
    const float* __restrict__ x, const int* __restrict__ seg_start,
    float* __restrict__ out)
{
    __shared__ v4f red[4 * 8];   // [wave][colgrp], 512 B

    const int s     = blockIdx.x;
    const int start = seg_start[s];
    const int len   = seg_start[s + 1] - start;
    if (len <= 0) return;   // empty segment: nothing to write

    const int tid  = (int)threadIdx.x;
    const int cg   = tid & 7;     // col group (4 floats)
    const int rg   = tid >> 3;    // row within a 32-row tile, 0..31
    const int wave = tid >> 6;    // 0..3
    const int lane = tid & 63;

    const v4f* __restrict__ xin  = (const v4f*)(x + (size_t)start * D);
    v4f* __restrict__       outv = (v4f*)(out + (size_t)start * D);

    const v4f NEGINF = {-INFINITY, -INFINITY, -INFINITY, -INFINITY};

    if (len <= 32 * K_CAP) {
        // ---- stage: all loads issued before any use (deep vmcnt pipeline).
        // Out-of-range tiles get -inf: max ignores them, exp gives 0. ----
        v4f st[K_CAP];   // fully unrolled -> static indices -> registers
        #pragma unroll
        for (int k = 0; k < K_CAP; ++k) {
            int r = rg + 32 * k;
            st[k] = (r < len) ? xin[r * 8 + cg] : NEGINF;
        }

        // ---- column max: regs -> wave shfl -> LDS across 4 waves ----
        v4f lmax = NEGINF;
        #pragma unroll
        for (int k = 0; k < K_CAP; ++k) lmax = v4max(lmax, st[k]);
        lmax = v4max(lmax, shfl_xor_v4(lmax, 8));
        lmax = v4max(lmax, shfl_xor_v4(lmax, 16));
        lmax = v4max(lmax, shfl_xor_v4(lmax, 32));
        if (lane < 8) red[wave * 8 + cg] = lmax;
        __syncthreads();
        v4f cmax = v4max(v4max(red[0 * 8 + cg], red[1 * 8 + cg]),
                         v4max(red[2 * 8 + cg], red[3 * 8 + cg]));
        __syncthreads();   // protect red[] reuse

        // ---- exp in registers + column sum (invalid tiles contribute 0) ----
        v4f lsum = {0.f, 0.f, 0.f, 0.f};
        #pragma unroll
        for (int k = 0; k < K_CAP; ++k) {
            v4f e;
            e.x = __expf(st[k].x - cmax.x);
            e.y = __expf(st[k].y - cmax.y);
            e.z = __expf(st[k].z - cmax.z);
            e.w = __expf(st[k].w - cmax.w);
            st[k] = e;
            lsum += e;
        }
        lsum += shfl_xor_v4(lsum, 8);
        lsum += shfl_xor_v4(lsum, 16);
        lsum += shfl_xor_v4(lsum, 32);
        if (lane < 8) red[wave * 8 + cg] = lsum;
        __syncthreads();
        v4f csum = (red[0 * 8 + cg] + red[1 * 8 + cg]) +
                   (red[2 * 8 + cg] + red[3 * 8 + cg]);
        v4f rn;
        rn.x = 1.f / (csum.x + EPSF);
        rn.y = 1.f / (csum.y + EPSF);
        rn.z = 1.f / (csum.z + EPSF);
        rn.w = 1.f / (csum.w + EPSF);

        // ---- scale + store (nontemporal: don't evict x from L3) ----
        #pragma unroll
        for (int k = 0; k < K_CAP; ++k) {
            int r = rg + 32 * k;
            if (r < len) {
                v4f e = st[k] * rn;
                __builtin_nontemporal_store(e, &outv[r * 8 + cg]);
            }
        }
    } else {
        // ---- fallback for oversized segments (>320 rows; with this input
        // max segment ~310, so this should never run — correctness only) ----
        v4f lmax = NEGINF;
        for (int r = rg; r < len; r += 32)
            lmax = v4max(lmax, xin[r * 8 + cg]);
        lmax = v4max(lmax, shfl_xor_v4(lmax, 8));
        lmax = v4max(lmax, shfl_xor_v4(lmax, 16));
        lmax = v4max(lmax, shfl_xor_v4(lmax, 32));
        if (lane < 8) red[wave * 8 + cg] = lmax;
        __syncthreads();
        v4f cmax = v4max(v4max(red[0 * 8 + cg], red[1 * 8 + cg]),
                         v4max(red[2 * 8 + cg], red[3 * 8 + cg]));
        __syncthreads();

        v4f lsum = {0.f, 0.f, 0.f, 0.f};
        for (int r = rg; r < len; r += 32) {
            v4f v = xin[r * 8 + cg];
            v4f e;
            e.x = __expf(v.x - cmax.x);
            e.y = __expf(v.y - cmax.y);
            e.z = __expf(v.z - cmax.z);
            e.w = __expf(v.w - cmax.w);
            outv[r * 8 + cg] = e;   // stage exp() in out
            lsum += e;
        }
        lsum += shfl_xor_v4(lsum, 8);
        lsum += shfl_xor_v4(lsum, 16);
        lsum += shfl_xor_v4(lsum, 32);
        if (lane < 8) red[wave * 8 + cg] = lsum;
        __syncthreads();
        v4f csum = (red[0 * 8 + cg] + red[1 * 8 + cg]) +
                   (red[2 * 8 + cg] + red[3 * 8 + cg]);
        v4f rn;
        rn.x = 1.f / (csum.x + EPSF);
        rn.y = 1.f / (csum.y + EPSF);
        rn.z = 1.f / (csum.z + EPSF);
        rn.w = 1.f / (csum.w + EPSF);

        for (int r = rg; r < len; r += 32) {
            v4f e = outv[r * 8 + cg];   // same thread wrote it; no fence needed
            outv[r * 8 + cg] = e * rn;
        }
    }
}

// ---------------------------------------------------------------------------
extern "C" void kernel_launch(void* const* d_in, const int* in_sizes, int n_in,
                              void* d_out, int out_size, void* d_ws, size_t ws_size,
                              hipStream_t stream) {
    const int*   batch = (const int*)d_in[0];
    const float* x     = (const float*)d_in[1];
    float*       out   = (float*)d_out;
    const int    N     = in_sizes[0];

    int* seg_start = (int*)d_ws;   // (NSEG+1) ints; re-initialized every call

    init_starts_kernel<<<(NSEG + 1 + 255) / 256, 256, 0, stream>>>(seg_start, N);
    find_starts_kernel<<<(N + 255) / 256, 256, 0, stream>>>(batch, seg_start, N);
    seg_softmax_reg<<<NSEG, BLK, 0, stream>>>(x, seg_start, out);
}